// Round 5
// baseline (925.311 us; speedup 1.0000x reference)
//
#include <hip/hip_runtime.h>

#define NB 32          // batch size B (fixed by problem)
#define BUCKET 128     // dsts per bucket => nbuckets = ceil(M/128) = 782
#define SLICE_W 20000  // src rows per slice => xt slice = 2.56 MB, fits 4 MiB XCD L2
#define MAXBINS 4096   // >= nslice*nbuckets = 5*782 = 3910
#define HCHUNK 16384   // hist: edges per block
#define PCHUNK 32768   // partition: edges per block
#define PBT 1024       // partition: threads per block
#define GCH 1024       // gather: staged edges per LDS chunk
// Edge record packs src_local (15 bits, < 20000) | dloc (7 bits, < 128) << 15.

// s / 20000 for s < 2^20 via magic multiply (verified at slice boundaries).
__device__ __forceinline__ int slice_of(int s) {
    return (int)(((unsigned long long)(unsigned)s * 6871948ull) >> 37);
}

// Agent-scope load: bypasses per-CU L1 (useless for random 2.56MB working set),
// served directly by the XCD L2. Verified in R4 that these DO cache in L2.
__device__ __forceinline__ float xld(const float* p) {
    return __hip_atomic_load(p, __ATOMIC_RELAXED, __HIP_MEMORY_SCOPE_AGENT);
}

// ---------------------------------------------------------------------------
// x (B, N) -> xt (N, B): 32x32 LDS tile transpose, coalesced read and write.
// ---------------------------------------------------------------------------
__global__ void transpose_x_kernel(const float* __restrict__ x,
                                   float* __restrict__ xt, int N) {
    __shared__ float tile[32][33];
    int n0 = blockIdx.x * 32;
    for (int i = threadIdx.y; i < 32; i += 8) {
        int n = n0 + threadIdx.x;
        tile[i][threadIdx.x] = (n < N) ? x[(size_t)i * N + n] : 0.f;
    }
    __syncthreads();
    for (int i = threadIdx.y; i < 32; i += 8) {
        int n = n0 + i;
        if (n < N) xt[(size_t)n * NB + threadIdx.x] = tile[threadIdx.x][i];
    }
}

// ---------------------------------------------------------------------------
// Histogram over bins (slice-major: bin = slice*nbuckets + dst/128) via LDS.
// ---------------------------------------------------------------------------
__global__ void hist_kernel(const int* __restrict__ src,
                            const int* __restrict__ dst,
                            int* __restrict__ bcount, int nnz, int nbins,
                            int nbuckets) {
    __shared__ int h[MAXBINS];
    int t = threadIdx.x;
    for (int j = t; j < nbins; j += 256) h[j] = 0;
    __syncthreads();
    int s0 = blockIdx.x * HCHUNK;
    int e0 = min(nnz, s0 + HCHUNK);
    for (int j = s0 + t; j < e0; j += 256)
        atomicAdd(&h[slice_of(src[j]) * nbuckets + (dst[j] >> 7)], 1);
    __syncthreads();
    for (int j = t; j < nbins; j += 256)
        if (h[j]) atomicAdd(&bcount[j], h[j]);
}

// ---------------------------------------------------------------------------
// Single-block exclusive scan over nbins (<=4096) counts -> boff, cursor=boff.
// ---------------------------------------------------------------------------
__global__ void scan_kernel(const int* __restrict__ bcount,
                            int* __restrict__ boff, int* __restrict__ cursor,
                            int nbins, int nnz) {
    __shared__ int lds[256];
    int t = threadIdx.x;
    int chunk = (nbins + 255) / 256;  // 16 for nbins=3910
    int base = t * chunk;
    int v[16];
    int s = 0;
    for (int j = 0; j < chunk; j++) {
        int idx = base + j;
        v[j] = (idx < nbins) ? bcount[idx] : 0;
        s += v[j];
    }
    lds[t] = s;
    __syncthreads();
    for (int d = 1; d < 256; d <<= 1) {
        int u = (t >= d) ? lds[t - d] : 0;
        __syncthreads();
        lds[t] += u;
        __syncthreads();
    }
    int ex = lds[t] - s;
    for (int j = 0; j < chunk; j++) {
        int idx = base + j;
        if (idx < nbins) {
            boff[idx] = ex;
            cursor[idx] = ex;
            ex += v[j];
        }
    }
    if (t == 255) boff[nbins] = nnz;
}

// ---------------------------------------------------------------------------
// Reservation-based partition into (slice, bucket) bins. Per 32K-edge block:
// LDS hist -> one global atomicAdd per nonempty bin reserves a run -> per-edge
// LDS cursor gives in-run position. Record: {src_local | dloc<<15, val_bits}.
// ---------------------------------------------------------------------------
__global__ void partition_kernel(const int* __restrict__ src,
                                 const int* __restrict__ dst,
                                 const float* __restrict__ vals,
                                 int* __restrict__ cursor,
                                 int2* __restrict__ bedge, int nnz, int nbins,
                                 int nbuckets) {
    __shared__ int h[MAXBINS];
    int t = threadIdx.x;
    for (int j = t; j < nbins; j += PBT) h[j] = 0;
    __syncthreads();
    int s0 = blockIdx.x * PCHUNK;
    int e0 = min(nnz, s0 + PCHUNK);
    for (int j = s0 + t; j < e0; j += PBT)
        atomicAdd(&h[slice_of(src[j]) * nbuckets + (dst[j] >> 7)], 1);
    __syncthreads();
    for (int j = t; j < nbins; j += PBT) {
        int c = h[j];
        h[j] = c ? atomicAdd(&cursor[j], c) : 0;  // h now holds run cursor
    }
    __syncthreads();
    for (int j = s0 + t; j < e0; j += PBT) {
        int s = src[j];
        int d = dst[j];
        int sl = slice_of(s);
        int bin = sl * nbuckets + (d >> 7);
        int pos = atomicAdd(&h[bin], 1);
        bedge[pos] =
            make_int2((s - sl * SLICE_W) | ((d & 127) << 15), __float_as_int(vals[j]));
    }
}

// ---------------------------------------------------------------------------
// One persistent block per bucket (128 dsts); all 782 blocks co-resident
// (~3 blocks/CU). Each block walks its 5 slice-segments in order, so the
// whole chip gathers from one 2.56 MB xt slice at a time => L2-resident.
// Accumulator (128 x 32, padded) persists in LDS across slices; bias is
// folded into the init; epilogue is plain coalesced float4 stores.
// ---------------------------------------------------------------------------
__global__ void __launch_bounds__(256, 4)
gather_kernel(const int2* __restrict__ bedge, const int* __restrict__ boff,
              const float* __restrict__ xt, const float* __restrict__ bias,
              float* __restrict__ out, int M, int nbuckets, int nslice) {
    __shared__ int4 est4[GCH / 2];        // 8 KB edge staging
    __shared__ float acc[BUCKET * 33];    // 16.9 KB accumulator, padded
    int2* est2 = (int2*)est4;
    int t = threadIdx.x;
    int k = blockIdx.x;
    int m0 = k * BUCKET;

    for (int j = t; j < BUCKET * 33; j += 256) {
        int dloc = j / 33;  // compile-time-const divisor -> magic mul
        int m = m0 + dloc;
        acc[j] = (m < M) ? bias[m] : 0.f;
    }

    int hw = t >> 5;  // half-wave 0..7
    int b = t & 31;   // batch lane

    for (int s = 0; s < nslice; s++) {
        int bin = s * nbuckets + k;
        int o = boff[bin];
        int n = boff[bin + 1] - o;
        const float* xts = xt + (size_t)s * SLICE_W * NB;
        for (int c0 = 0; c0 < n; c0 += GCH) {
            int nc = min(n - c0, GCH);
            __syncthreads();  // staging reuse (+first-iter acc visibility)
            for (int j = t; j < nc; j += 256) est2[j] = bedge[o + c0 + j];
            __syncthreads();

            int seg = ((nc + 15) >> 4) << 1;  // even => int4-aligned start
            int st = hw * seg;
            int en = min(st + seg, nc);
            int i = st;
            for (; i + 8 <= en; i += 8) {
                int g = i >> 1;
                int4 q0 = est4[g + 0];
                int4 q1 = est4[g + 1];
                int4 q2 = est4[g + 2];
                int4 q3 = est4[g + 3];
                float x0 = xld(&xts[(size_t)(q0.x & 0x7FFF) * NB + b]);
                float x1 = xld(&xts[(size_t)(q0.z & 0x7FFF) * NB + b]);
                float x2 = xld(&xts[(size_t)(q1.x & 0x7FFF) * NB + b]);
                float x3 = xld(&xts[(size_t)(q1.z & 0x7FFF) * NB + b]);
                float x4 = xld(&xts[(size_t)(q2.x & 0x7FFF) * NB + b]);
                float x5 = xld(&xts[(size_t)(q2.z & 0x7FFF) * NB + b]);
                float x6 = xld(&xts[(size_t)(q3.x & 0x7FFF) * NB + b]);
                float x7 = xld(&xts[(size_t)(q3.z & 0x7FFF) * NB + b]);
                atomicAdd(&acc[((unsigned)q0.x >> 15) * 33 + b], __int_as_float(q0.y) * x0);
                atomicAdd(&acc[((unsigned)q0.z >> 15) * 33 + b], __int_as_float(q0.w) * x1);
                atomicAdd(&acc[((unsigned)q1.x >> 15) * 33 + b], __int_as_float(q1.y) * x2);
                atomicAdd(&acc[((unsigned)q1.z >> 15) * 33 + b], __int_as_float(q1.w) * x3);
                atomicAdd(&acc[((unsigned)q2.x >> 15) * 33 + b], __int_as_float(q2.y) * x4);
                atomicAdd(&acc[((unsigned)q2.z >> 15) * 33 + b], __int_as_float(q2.w) * x5);
                atomicAdd(&acc[((unsigned)q3.x >> 15) * 33 + b], __int_as_float(q3.y) * x6);
                atomicAdd(&acc[((unsigned)q3.z >> 15) * 33 + b], __int_as_float(q3.w) * x7);
            }
            for (; i < en; i++) {
                int2 e = est2[i];
                float xv = xld(&xts[(size_t)(e.x & 0x7FFF) * NB + b]);
                atomicAdd(&acc[((unsigned)e.x >> 15) * 33 + b], __int_as_float(e.y) * xv);
            }
        }
    }
    __syncthreads();

    // Epilogue: thread t -> batch b2 = t>>3, 16 consecutive m's starting c0.
    int b2 = t >> 3;
    int c0 = (t & 7) * 16;
    for (int q = 0; q < 16; q += 4) {
        int m = m0 + c0 + q;
        if ((M % 4 == 0) && (m + 3 < M)) {
            float4 o4;
            o4.x = acc[(c0 + q + 0) * 33 + b2];
            o4.y = acc[(c0 + q + 1) * 33 + b2];
            o4.z = acc[(c0 + q + 2) * 33 + b2];
            o4.w = acc[(c0 + q + 3) * 33 + b2];
            *(float4*)&out[(size_t)b2 * M + m] = o4;
        } else {
            for (int r = 0; r < 4; r++)
                if (m + r < M)
                    out[(size_t)b2 * M + m + r] = acc[(c0 + q + r) * 33 + b2];
        }
    }
}

extern "C" void kernel_launch(void* const* d_in, const int* in_sizes, int n_in,
                              void* d_out, int out_size, void* d_ws, size_t ws_size,
                              hipStream_t stream) {
    const float* x       = (const float*)d_in[0];   // (B, N, 1) fp32
    const int*   indices = (const int*)  d_in[1];   // (2, NNZ) int32
    const float* vals    = (const float*)d_in[2];   // (NNZ,) fp32
    const float* bias    = (const float*)d_in[3];   // (M, 1) fp32
    float* out = (float*)d_out;                     // (B, M, 1) fp32

    int nnz = in_sizes[1] / 2;
    int N   = in_sizes[0] / NB;
    int M   = in_sizes[3];

    const int* src = indices;
    const int* dst = indices + nnz;

    int nbuckets = (M + BUCKET - 1) / BUCKET;        // 782
    int nslice   = (N + SLICE_W - 1) / SLICE_W;      // 5
    int nbins    = nslice * nbuckets;                // 3910 (<= MAXBINS)

    // workspace layout
    float* xt     = (float*)d_ws;                    // N*32 floats (12.8 MB)
    int*   bcount = (int*)(xt + (size_t)N * NB);     // nbins
    int*   boff   = bcount + nbins;                  // nbins+1
    int*   cursor = boff + nbins + 1;                // nbins
    size_t intoff = (size_t)(3 * nbins + 1);
    intoff = (intoff + 3) & ~(size_t)3;              // 16B-align bedge
    int2*  bedge  = (int2*)(bcount + intoff);        // nnz int2 (25.6 MB)

    hipMemsetAsync(bcount, 0, (size_t)nbins * sizeof(int), stream);

    transpose_x_kernel<<<(N + 31) / 32, dim3(32, 8), 0, stream>>>(x, xt, N);

    hist_kernel<<<(nnz + HCHUNK - 1) / HCHUNK, 256, 0, stream>>>(
        src, dst, bcount, nnz, nbins, nbuckets);
    scan_kernel<<<1, 256, 0, stream>>>(bcount, boff, cursor, nbins, nnz);
    partition_kernel<<<(nnz + PCHUNK - 1) / PCHUNK, PBT, 0, stream>>>(
        src, dst, vals, cursor, bedge, nnz, nbins, nbuckets);
    gather_kernel<<<nbuckets, 256, 0, stream>>>(bedge, boff, xt, bias, out, M,
                                                nbuckets, nslice);
}